// Round 1
// baseline (1239.463 us; speedup 1.0000x reference)
//
#include <hip/hip_runtime.h>

#define DI __device__ __forceinline__

DI float frcp(float x){ return __builtin_amdgcn_rcpf(x); }
DI float frsq(float x){ return __builtin_amdgcn_rsqf(x); }
DI float sigmf(float x){ return frcp(1.f + __expf(-x)); }
DI float tanhf_(float x){ return 1.f - 2.f*frcp(__expf(2.f*x) + 1.f); }

struct Params {
  const float* __restrict__ x;
  const float* __restrict__ Wih0; const float* __restrict__ Whh0;
  const float* __restrict__ bih0; const float* __restrict__ bhh0;
  const float* __restrict__ Wih1; const float* __restrict__ Whh1;
  const float* __restrict__ bih1; const float* __restrict__ bhh1;
  const float* __restrict__ fcW;  const float* __restrict__ fcb;
  const float* __restrict__ W2;   const float* __restrict__ b2;
  const float* __restrict__ g2;   const float* __restrict__ be2;
  const float* __restrict__ W3;   const float* __restrict__ b3;
  const float* __restrict__ g3;   const float* __restrict__ be3;
  const float* __restrict__ W1f;  const float* __restrict__ b1f;
  const float* __restrict__ g1f;  const float* __restrict__ be1f;
  const float* __restrict__ W2f;  const float* __restrict__ b2f;
  const float* __restrict__ g2f;  const float* __restrict__ be2f;
  const float* __restrict__ W3f;  const float* __restrict__ b3f;
  const float* __restrict__ g3f;  const float* __restrict__ be3f;
  float* __restrict__ out;
};

// One LSTM cell step for all 32 hidden units of one sample.
// All register-array indices are compile-time constants (fully unrolled).
template<int IN>
DI void lstm_step(const float* __restrict__ Wih, const float* __restrict__ Whh,
                  const float* __restrict__ bih, const float* __restrict__ bhh,
                  const float* xin, const float* hin, float* c, float* hout){
  #pragma unroll
  for(int j=0;j<32;j++){
    float ai = bih[j]      + bhh[j];
    float af = bih[32+j]   + bhh[32+j];
    float ag = bih[64+j]   + bhh[64+j];
    float ao = bih[96+j]   + bhh[96+j];
    #pragma unroll
    for(int k=0;k<IN;k++){
      float xv = xin[k];
      ai += xv*Wih[j*IN+k];
      af += xv*Wih[(32+j)*IN+k];
      ag += xv*Wih[(64+j)*IN+k];
      ao += xv*Wih[(96+j)*IN+k];
    }
    #pragma unroll
    for(int k=0;k<32;k++){
      float hv = hin[k];
      ai += hv*Whh[j*32+k];
      af += hv*Whh[(32+j)*32+k];
      ag += hv*Whh[(64+j)*32+k];
      ao += hv*Whh[(96+j)*32+k];
    }
    float cc = sigmf(af)*c[j] + sigmf(ai)*tanhf_(ag);
    c[j] = cc;
    hout[j] = sigmf(ao)*tanhf_(cc);
  }
}

// conv2 (4 out-channels) at output column w for one sample.
// Boundary handled by clamped (always in-bounds) load + select -> no divergence.
DI void conv4(const float* __restrict__ xr, int w,
              const float* __restrict__ W2, const float* __restrict__ b2, float* a){
  float win[3][5];
  #pragma unroll
  for(int r=0;r<3;r++){
    #pragma unroll
    for(int kk=0;kk<5;kk++){
      int c = w - 2 + kk;                    // csi column, valid range [0,101]
      int cc = c < 0 ? 0 : (c > 101 ? 101 : c);
      float v = xr[r*116 + 1 + cc];          // csi[r][c] = x[.., r, 1+c]
      win[r][kk] = (c == cc) ? v : 0.f;      // zero-pad
    }
  }
  #pragma unroll
  for(int o=0;o<4;o++){
    float s = b2[o];
    #pragma unroll
    for(int r=0;r<3;r++){
      #pragma unroll
      for(int kk=0;kk<5;kk++) s += win[r][kk]*W2[o*15 + r*5 + kk];
    }
    a[o] = s;
  }
}

DI void ln_relu32(float* a, const float* __restrict__ g, const float* __restrict__ be){
  float s=0.f, q=0.f;
  #pragma unroll
  for(int j=0;j<32;j++){ s += a[j]; q += a[j]*a[j]; }
  float m  = s*(1.f/32.f);
  float va = q*(1.f/32.f) - m*m;
  float rs = frsq(va + 1e-5f);
  #pragma unroll
  for(int j=0;j<32;j++) a[j] = fmaxf((a[j]-m)*rs*g[j] + be[j], 0.f);
}

// 1 thread = 1 sample. 128 threads/block -> static LDS 128*103*4 = 52.7 KB.
__global__ __launch_bounds__(128,1) void csnet_kernel(Params p){
  const int tid = threadIdx.x;
  const int b = blockIdx.x*128 + tid;
  const float* __restrict__ xr = p.x + (size_t)b*348;
  __shared__ float sbuf[128*103];            // stride 103: bank-conflict-free
  float* my = &sbuf[tid*103];

  // ---------------- LSTM (2 layers, 4 steps) ----------------
  float h0[32], c0[32], h1[32], c1[32];
  #pragma unroll
  for(int j=0;j<32;j++){ h0[j]=0.f; c0[j]=0.f; h1[j]=0.f; c1[j]=0.f; }
  #pragma unroll 1
  for(int t=0;t<4;t++){
    float xt[3];
    #pragma unroll
    for(int d=0;d<3;d++) xt[d] = xr[220 + t*3 + d];   // pos[t] = x[b,0,1,104+3t+d]
    float hA[32], hB[32];
    lstm_step<3 >(p.Wih0,p.Whh0,p.bih0,p.bhh0, xt, h0, c0, hA);
    lstm_step<32>(p.Wih1,p.Whh1,p.bih1,p.bhh1, hA, h1, c1, hB);
    #pragma unroll
    for(int j=0;j<32;j++){ h0[j]=hA[j]; h1[j]=hB[j]; }
  }
  // pos_p = h1 @ fcW.T + fcb ; vel = (pos_p - pos_r)/0.1
  float pp[3], vel[3];
  #pragma unroll
  for(int d=0;d<3;d++){
    float a = p.fcb[d];
    #pragma unroll
    for(int j=0;j<32;j++) a += h1[j]*p.fcW[d*32+j];
    pp[d]  = a;
    vel[d] = (a - xr[229+d])*10.f;           // pos_r = x[b,0,1,113+d]
  }

  // ---------------- conv2 pass 1: LN stats over 4*102 ----------------
  float s1 = 0.f, s2 = 0.f;
  #pragma unroll 2
  for(int w=0; w<102; ++w){
    float a[4];
    conv4(xr, w, p.W2, p.b2, a);
    #pragma unroll
    for(int o=0;o<4;o++){ s1 += a[o]; s2 += a[o]*a[o]; }
  }
  float m2  = s1*(1.f/408.f);
  float va2 = s2*(1.f/408.f) - m2*m2;
  float rs2 = frsq(va2 + 1e-5f);

  // ---------------- conv2 pass 2 (recompute) + LN/relu + cv3 ----------------
  float w3v[4];
  #pragma unroll
  for(int o=0;o<4;o++) w3v[o] = p.W3[o];
  float b3v = p.b3[0];
  float s31=0.f, s32=0.f;
  #pragma unroll 2
  for(int w=0; w<102; ++w){
    float a[4];
    conv4(xr, w, p.W2, p.b2, a);
    float o3 = b3v;
    #pragma unroll
    for(int o=0;o<4;o++){
      float nv = (a[o]-m2)*rs2*p.g2[o*102+w] + p.be2[o*102+w];
      o3 += fmaxf(nv, 0.f)*w3v[o];
    }
    s31 += o3; s32 += o3*o3;
    my[w] = o3;                               // out3 pre-LN, thread-private slice
  }
  float m3  = s31*(1.f/102.f);
  float va3 = s32*(1.f/102.f) - m3*m3;
  float rs3 = frsq(va3 + 1e-5f);

  // ---------------- f1: 108 -> 32, LN, relu ----------------
  float a1[32];
  #pragma unroll
  for(int j=0;j<32;j++) a1[j] = p.b1f[j];
  #pragma unroll 4
  for(int w=0; w<102; ++w){
    float v = (my[w]-m3)*rs3*p.g3[w] + p.be3[w];   // LN3 + relu of out3
    v = fmaxf(v, 0.f);
    #pragma unroll
    for(int j=0;j<32;j++) a1[j] += v*p.W1f[j*108+w];
  }
  #pragma unroll
  for(int d=0;d<3;d++){
    #pragma unroll
    for(int j=0;j<32;j++) a1[j] += pp[d]*p.W1f[j*108+102+d];
  }
  #pragma unroll
  for(int d=0;d<3;d++){
    #pragma unroll
    for(int j=0;j<32;j++) a1[j] += vel[d]*p.W1f[j*108+105+d];
  }
  ln_relu32(a1, p.g1f, p.be1f);

  // ---------------- f2: 32 -> 32, LN, relu ----------------
  float a2[32];
  #pragma unroll
  for(int j=0;j<32;j++){
    float a = p.b2f[j];
    #pragma unroll
    for(int k=0;k<32;k++) a += a1[k]*p.W2f[j*32+k];
    a2[j] = a;
  }
  ln_relu32(a2, p.g2f, p.be2f);

  // ---------------- f3: 32 -> 102, LN, sigmoid ----------------
  float t1=0.f, t2=0.f;
  #pragma unroll 2
  for(int w=0; w<102; ++w){
    float a = p.b3f[w];
    #pragma unroll
    for(int j=0;j<32;j++) a += a2[j]*p.W3f[w*32+j];
    t1 += a; t2 += a*a;
    my[w] = a;
  }
  float mf  = t1*(1.f/102.f);
  float vaf = t2*(1.f/102.f) - mf*mf;
  float rsf = frsq(vaf + 1e-5f);
  #pragma unroll 4
  for(int w=0; w<102; ++w){
    float u = (my[w]-mf)*rsf*p.g3f[w] + p.be3f[w];
    my[w] = sigmf(u);
  }
  __syncthreads();

  // ---------------- coalesced float4 transpose-store ----------------
  // block covers samples [blockIdx*128, +128) -> 13056 contiguous output floats
  float* op = p.out + (size_t)blockIdx.x*13056;
  #pragma unroll 1
  for(int m=0;m<26;m++){
    int i4 = tid + 128*m;
    if(i4 < 3264){
      int i0 = i4*4;
      float4 v;
      #pragma unroll
      for(int e=0;e<4;e++){
        int idx = i0 + e;
        int sm = idx/102;                    // magic-mul div (constant divisor)
        int wd = idx - sm*102;
        ((float*)&v)[e] = sbuf[sm*103 + wd];
      }
      *reinterpret_cast<float4*>(op + i0) = v;
    }
  }
}

extern "C" void kernel_launch(void* const* d_in, const int* in_sizes, int n_in,
                              void* d_out, int out_size, void* d_ws, size_t ws_size,
                              hipStream_t stream) {
  (void)in_sizes; (void)n_in; (void)d_ws; (void)ws_size; (void)out_size;
  Params p;
  p.x    = (const float*)d_in[0];
  p.Wih0 = (const float*)d_in[1];  p.Whh0 = (const float*)d_in[2];
  p.bih0 = (const float*)d_in[3];  p.bhh0 = (const float*)d_in[4];
  p.Wih1 = (const float*)d_in[5];  p.Whh1 = (const float*)d_in[6];
  p.bih1 = (const float*)d_in[7];  p.bhh1 = (const float*)d_in[8];
  p.fcW  = (const float*)d_in[9];  p.fcb  = (const float*)d_in[10];
  p.W2   = (const float*)d_in[11]; p.b2   = (const float*)d_in[12];
  p.g2   = (const float*)d_in[13]; p.be2  = (const float*)d_in[14];
  p.W3   = (const float*)d_in[15]; p.b3   = (const float*)d_in[16];
  p.g3   = (const float*)d_in[17]; p.be3  = (const float*)d_in[18];
  p.W1f  = (const float*)d_in[19]; p.b1f  = (const float*)d_in[20];
  p.g1f  = (const float*)d_in[21]; p.be1f = (const float*)d_in[22];
  p.W2f  = (const float*)d_in[23]; p.b2f  = (const float*)d_in[24];
  p.g2f  = (const float*)d_in[25]; p.be2f = (const float*)d_in[26];
  p.W3f  = (const float*)d_in[27]; p.b3f  = (const float*)d_in[28];
  p.g3f  = (const float*)d_in[29]; p.be3f = (const float*)d_in[30];
  p.out  = (float*)d_out;
  // 65536 samples / 128 threads = 512 blocks (exactly 1 wave/SIMD device-wide)
  csnet_kernel<<<512, 128, 0, stream>>>(p);
}

// Round 2
// 928.270 us; speedup vs baseline: 1.3352x; 1.3352x over previous
//
#include <hip/hip_runtime.h>

#define DI __device__ __forceinline__

#define NSAMP 65536

DI float frcp(float x){ return __builtin_amdgcn_rcpf(x); }
DI float frsq(float x){ return __builtin_amdgcn_rsqf(x); }
DI float sigmf(float x){ return frcp(1.f + __expf(-x)); }
DI float tanhf_(float x){ return 1.f - 2.f*frcp(__expf(2.f*x) + 1.f); }

struct Params {
  const float* __restrict__ x;
  const float* __restrict__ xT;    // SoA packed features [320][NSAMP] (ws)
  const float* __restrict__ w1ft;  // W1f transposed [108][32] (ws tail)
  const float* __restrict__ Wih0; const float* __restrict__ Whh0;
  const float* __restrict__ bih0; const float* __restrict__ bhh0;
  const float* __restrict__ Wih1; const float* __restrict__ Whh1;
  const float* __restrict__ bih1; const float* __restrict__ bhh1;
  const float* __restrict__ fcW;  const float* __restrict__ fcb;
  const float* __restrict__ W2;   const float* __restrict__ b2;
  const float* __restrict__ g2;   const float* __restrict__ be2;
  const float* __restrict__ W3;   const float* __restrict__ b3;
  const float* __restrict__ g3;   const float* __restrict__ be3;
  const float* __restrict__ W1f;  const float* __restrict__ b1f;
  const float* __restrict__ g1f;  const float* __restrict__ be1f;
  const float* __restrict__ W2f;  const float* __restrict__ b2f;
  const float* __restrict__ g2f;  const float* __restrict__ be2f;
  const float* __restrict__ W3f;  const float* __restrict__ b3f;
  const float* __restrict__ g3f;  const float* __restrict__ be3f;
  float* __restrict__ out;
};

// ---- feature accessors: SoA (coalesced) or AoS fallback ----
template<bool SOA>
DI float ldcsi(const float* __restrict__ base, int b, int r, int c){
  if constexpr(SOA) return base[(size_t)(r*102 + c)*NSAMP + b];
  else              return base[(size_t)b*348 + r*116 + 1 + c];
}
template<bool SOA>
DI float ldpos(const float* __restrict__ base, int b, int k){
  if constexpr(SOA) return base[(size_t)(306 + k)*NSAMP + b];
  else              return base[(size_t)b*348 + 220 + k];
}

// ---------- pack kernel: x (AoS) -> xT (SoA), plus W1f transpose ----------
__global__ __launch_bounds__(256,1) void pack_kernel(const float* __restrict__ x,
                                                     float* __restrict__ xT,
                                                     const float* __restrict__ W1f,
                                                     float* __restrict__ w1ft){
  __shared__ float s[64*349];                 // 89.3 KB, odd stride
  const int b0 = blockIdx.x*64;
  // coalesced float4 load of 64 sample rows (64*348 floats)
  const float4* src = reinterpret_cast<const float4*>(x + (size_t)b0*348);
  for(int i=threadIdx.x; i<64*87; i+=256){
    float4 v = src[i];
    int smp = i/87; int off = (i - smp*87)*4;
    float* d = &s[smp*349 + off];
    d[0]=v.x; d[1]=v.y; d[2]=v.z; d[3]=v.w;
  }
  __syncthreads();
  // transposed write: 320 features x 64 samples, lane = sample -> coalesced
  for(int i=threadIdx.x; i<320*64; i+=256){
    int f = i>>6; int sI = i&63;
    int off;
    if(f < 306){ int r = f/102; off = r*14 + 1 + f; }   // r*116+1+(f-102r)
    else if(f < 318) off = 220 + (f-306);
    else off = 0;                                        // pad
    xT[(size_t)f*NSAMP + b0 + sI] = s[sI*349 + off];
  }
  // W1f transpose (tiny, block 0 only)
  if(blockIdx.x == 0){
    for(int i=threadIdx.x; i<108*32; i+=256){
      int w = i>>5, j = i&31;
      w1ft[w*32 + j] = W1f[j*108 + w];
    }
  }
}

// One LSTM cell step for all 32 hidden units of one sample.
template<int IN>
DI void lstm_step(const float* __restrict__ Wih, const float* __restrict__ Whh,
                  const float* __restrict__ bih, const float* __restrict__ bhh,
                  const float* xin, const float* hin, float* c, float* hout){
  #pragma unroll
  for(int j=0;j<32;j++){
    float ai = bih[j]      + bhh[j];
    float af = bih[32+j]   + bhh[32+j];
    float ag = bih[64+j]   + bhh[64+j];
    float ao = bih[96+j]   + bhh[96+j];
    #pragma unroll
    for(int k=0;k<IN;k++){
      float xv = xin[k];
      ai += xv*Wih[j*IN+k];
      af += xv*Wih[(32+j)*IN+k];
      ag += xv*Wih[(64+j)*IN+k];
      ao += xv*Wih[(96+j)*IN+k];
    }
    #pragma unroll
    for(int k=0;k<32;k++){
      float hv = hin[k];
      ai += hv*Whh[j*32+k];
      af += hv*Whh[(32+j)*32+k];
      ag += hv*Whh[(64+j)*32+k];
      ao += hv*Whh[(96+j)*32+k];
    }
    float cc = sigmf(af)*c[j] + sigmf(ai)*tanhf_(ag);
    c[j] = cc;
    hout[j] = sigmf(ao)*tanhf_(cc);
  }
}

DI void ln_relu32(float* a, const float* __restrict__ g, const float* __restrict__ be){
  float s=0.f, q=0.f;
  #pragma unroll
  for(int j=0;j<32;j++){ s += a[j]; q += a[j]*a[j]; }
  float m  = s*(1.f/32.f);
  float va = q*(1.f/32.f) - m*m;
  float rs = frsq(va + 1e-5f);
  #pragma unroll
  for(int j=0;j<32;j++) a[j] = fmaxf((a[j]-m)*rs*g[j] + be[j], 0.f);
}

// 1 thread = 1 sample; sliding-window conv; SoA coalesced x reads.
template<bool SOA>
__global__ __launch_bounds__(128,1) void csnet_main(Params p){
  const int tid = threadIdx.x;
  const int b = blockIdx.x*128 + tid;
  const float* __restrict__ xb = SOA ? p.xT : p.x;
  __shared__ float sbuf[128*103];            // stride 103: conflict-free
  float* my = &sbuf[tid*103];

  // ---------------- LSTM (2 layers, 4 steps) ----------------
  float h0[32], c0[32], h1[32], c1[32];
  #pragma unroll
  for(int j=0;j<32;j++){ h0[j]=0.f; c0[j]=0.f; h1[j]=0.f; c1[j]=0.f; }
  #pragma unroll 1
  for(int t=0;t<4;t++){
    float xt[3];
    #pragma unroll
    for(int d=0;d<3;d++) xt[d] = ldpos<SOA>(xb, b, t*3+d);
    float hA[32], hB[32];
    lstm_step<3 >(p.Wih0,p.Whh0,p.bih0,p.bhh0, xt, h0, c0, hA);
    lstm_step<32>(p.Wih1,p.Whh1,p.bih1,p.bhh1, hA, h1, c1, hB);
    #pragma unroll
    for(int j=0;j<32;j++){ h0[j]=hA[j]; h1[j]=hB[j]; }
  }
  float pp[3], vel[3];
  #pragma unroll
  for(int d=0;d<3;d++){
    float a = p.fcb[d];
    #pragma unroll
    for(int j=0;j<32;j++) a += h1[j]*p.fcW[d*32+j];
    pp[d]  = a;
    vel[d] = (a - ldpos<SOA>(xb, b, 9+d))*10.f;
  }

  // ---------------- conv2 pass 1: LN stats (sliding window) ----------------
  float s1 = 0.f, s2 = 0.f;
  {
    float u0[3],u1[3],u2[3],u3[3],u4[3];
    #pragma unroll
    for(int r=0;r<3;r++){
      u0[r]=0.f; u1[r]=0.f;
      u2[r]=ldcsi<SOA>(xb,b,r,0);
      u3[r]=ldcsi<SOA>(xb,b,r,1);
      u4[r]=ldcsi<SOA>(xb,b,r,2);
    }
    #pragma unroll 2
    for(int w=0; w<102; ++w){
      #pragma unroll
      for(int o=0;o<4;o++){
        const float* Wo = &p.W2[o*15];
        float s = p.b2[o];
        #pragma unroll
        for(int r=0;r<3;r++)
          s += u0[r]*Wo[r*5+0]+u1[r]*Wo[r*5+1]+u2[r]*Wo[r*5+2]+u3[r]*Wo[r*5+3]+u4[r]*Wo[r*5+4];
        s1 += s; s2 += s*s;
      }
      bool in = (w+3) < 102;
      #pragma unroll
      for(int r=0;r<3;r++){
        u0[r]=u1[r]; u1[r]=u2[r]; u2[r]=u3[r]; u3[r]=u4[r];
        u4[r] = in ? ldcsi<SOA>(xb,b,r,(w+3)<102?(w+3):101) : 0.f;
      }
    }
  }
  float m2  = s1*(1.f/408.f);
  float va2 = s2*(1.f/408.f) - m2*m2;
  float rs2 = frsq(va2 + 1e-5f);

  // ------------- conv2 pass 2 (recompute) + LN/relu + cv3 -------------
  float w3v[4];
  #pragma unroll
  for(int o=0;o<4;o++) w3v[o] = p.W3[o];
  float b3v = p.b3[0];
  float s31=0.f, s32=0.f;
  {
    float u0[3],u1[3],u2[3],u3[3],u4[3];
    #pragma unroll
    for(int r=0;r<3;r++){
      u0[r]=0.f; u1[r]=0.f;
      u2[r]=ldcsi<SOA>(xb,b,r,0);
      u3[r]=ldcsi<SOA>(xb,b,r,1);
      u4[r]=ldcsi<SOA>(xb,b,r,2);
    }
    #pragma unroll 2
    for(int w=0; w<102; ++w){
      float o3 = b3v;
      #pragma unroll
      for(int o=0;o<4;o++){
        const float* Wo = &p.W2[o*15];
        float s = p.b2[o];
        #pragma unroll
        for(int r=0;r<3;r++)
          s += u0[r]*Wo[r*5+0]+u1[r]*Wo[r*5+1]+u2[r]*Wo[r*5+2]+u3[r]*Wo[r*5+3]+u4[r]*Wo[r*5+4];
        float nv = (s - m2)*rs2*p.g2[o*102+w] + p.be2[o*102+w];
        o3 += fmaxf(nv, 0.f)*w3v[o];
      }
      s31 += o3; s32 += o3*o3;
      my[w] = o3;
      bool in = (w+3) < 102;
      #pragma unroll
      for(int r=0;r<3;r++){
        u0[r]=u1[r]; u1[r]=u2[r]; u2[r]=u3[r]; u3[r]=u4[r];
        u4[r] = in ? ldcsi<SOA>(xb,b,r,(w+3)<102?(w+3):101) : 0.f;
      }
    }
  }
  float m3  = s31*(1.f/102.f);
  float va3 = s32*(1.f/102.f) - m3*m3;
  float rs3 = frsq(va3 + 1e-5f);

  // ---------------- f1: 108 -> 32, LN, relu ----------------
  float a1[32];
  #pragma unroll
  for(int j=0;j<32;j++) a1[j] = p.b1f[j];
  #pragma unroll 2
  for(int w=0; w<102; ++w){
    float v = (my[w]-m3)*rs3*p.g3[w] + p.be3[w];
    v = fmaxf(v, 0.f);
    #pragma unroll
    for(int j=0;j<32;j++)
      a1[j] += v * (SOA ? p.w1ft[w*32+j] : p.W1f[j*108+w]);
  }
  #pragma unroll
  for(int d=0;d<3;d++){
    #pragma unroll
    for(int j=0;j<32;j++)
      a1[j] += pp[d]  * (SOA ? p.w1ft[(102+d)*32+j] : p.W1f[j*108+102+d]);
  }
  #pragma unroll
  for(int d=0;d<3;d++){
    #pragma unroll
    for(int j=0;j<32;j++)
      a1[j] += vel[d] * (SOA ? p.w1ft[(105+d)*32+j] : p.W1f[j*108+105+d]);
  }
  ln_relu32(a1, p.g1f, p.be1f);

  // ---------------- f2: 32 -> 32, LN, relu ----------------
  float a2[32];
  #pragma unroll
  for(int j=0;j<32;j++){
    float a = p.b2f[j];
    #pragma unroll
    for(int k=0;k<32;k++) a += a1[k]*p.W2f[j*32+k];
    a2[j] = a;
  }
  ln_relu32(a2, p.g2f, p.be2f);

  // ---------------- f3: 32 -> 102, LN, sigmoid ----------------
  float t1=0.f, t2=0.f;
  #pragma unroll 2
  for(int w=0; w<102; ++w){
    float a = p.b3f[w];
    #pragma unroll
    for(int j=0;j<32;j++) a += a2[j]*p.W3f[w*32+j];
    t1 += a; t2 += a*a;
    my[w] = a;
  }
  float mf  = t1*(1.f/102.f);
  float vaf = t2*(1.f/102.f) - mf*mf;
  float rsf = frsq(vaf + 1e-5f);
  #pragma unroll 4
  for(int w=0; w<102; ++w){
    float u = (my[w]-mf)*rsf*p.g3f[w] + p.be3f[w];
    my[w] = sigmf(u);
  }
  __syncthreads();

  // ---------------- coalesced float4 transpose-store ----------------
  float* op = p.out + (size_t)blockIdx.x*13056;
  #pragma unroll 1
  for(int m=0;m<26;m++){
    int i4 = tid + 128*m;
    if(i4 < 3264){
      int i0 = i4*4;
      float4 v;
      #pragma unroll
      for(int e=0;e<4;e++){
        int idx = i0 + e;
        int sm = idx/102;
        int wd = idx - sm*102;
        ((float*)&v)[e] = sbuf[sm*103 + wd];
      }
      *reinterpret_cast<float4*>(op + i0) = v;
    }
  }
}

extern "C" void kernel_launch(void* const* d_in, const int* in_sizes, int n_in,
                              void* d_out, int out_size, void* d_ws, size_t ws_size,
                              hipStream_t stream) {
  (void)in_sizes; (void)n_in; (void)out_size;
  Params p;
  p.x    = (const float*)d_in[0];
  p.Wih0 = (const float*)d_in[1];  p.Whh0 = (const float*)d_in[2];
  p.bih0 = (const float*)d_in[3];  p.bhh0 = (const float*)d_in[4];
  p.Wih1 = (const float*)d_in[5];  p.Whh1 = (const float*)d_in[6];
  p.bih1 = (const float*)d_in[7];  p.bhh1 = (const float*)d_in[8];
  p.fcW  = (const float*)d_in[9];  p.fcb  = (const float*)d_in[10];
  p.W2   = (const float*)d_in[11]; p.b2   = (const float*)d_in[12];
  p.g2   = (const float*)d_in[13]; p.be2  = (const float*)d_in[14];
  p.W3   = (const float*)d_in[15]; p.b3   = (const float*)d_in[16];
  p.g3   = (const float*)d_in[17]; p.be3  = (const float*)d_in[18];
  p.W1f  = (const float*)d_in[19]; p.b1f  = (const float*)d_in[20];
  p.g1f  = (const float*)d_in[21]; p.be1f = (const float*)d_in[22];
  p.W2f  = (const float*)d_in[23]; p.b2f  = (const float*)d_in[24];
  p.g2f  = (const float*)d_in[25]; p.be2f = (const float*)d_in[26];
  p.W3f  = (const float*)d_in[27]; p.b3f  = (const float*)d_in[28];
  p.g3f  = (const float*)d_in[29]; p.be3f = (const float*)d_in[30];
  p.out  = (float*)d_out;

  const size_t need = ((size_t)320*NSAMP + 108*32)*sizeof(float);
  if(ws_size >= need){
    float* xT   = (float*)d_ws;
    float* w1ft = xT + (size_t)320*NSAMP;
    p.xT = xT; p.w1ft = w1ft;
    pack_kernel<<<NSAMP/64, 256, 0, stream>>>(p.x, xT, p.W1f, w1ft);
    csnet_main<true><<<NSAMP/128, 128, 0, stream>>>(p);
  } else {
    p.xT = nullptr; p.w1ft = nullptr;
    csnet_main<false><<<NSAMP/128, 128, 0, stream>>>(p);
  }
}